// Round 1
// baseline (268.989 us; speedup 1.0000x reference)
//
#include <hip/hip_runtime.h>

// Problem constants (from reference)
#define N_PTS 1600
#define NSIDE 40
#define SNUM  512
#define BNUM  64
#define C1D   20
#define WID   128

__device__ __forceinline__ float silu_f(float x){ return x / (1.f + __expf(-x)); }
__device__ __forceinline__ void fma4(float4& a, float s, const float4 w){
    a.x += s*w.x; a.y += s*w.y; a.z += s*w.z; a.w += s*w.w;
}

// ---------------------------------------------------------------------------
// K0: transpose data [64][1600] -> dataT [1600][64]; compute h2 = silu(v0e@s_w1+b1) [512][128]
// ---------------------------------------------------------------------------
__global__ __launch_bounds__(256) void k0_prep(
    const float* __restrict__ data, const float* __restrict__ v0,
    const float* __restrict__ s_w1, const float* __restrict__ s_b1,
    float* __restrict__ dataT, float* __restrict__ h2g)
{
    const int g = blockIdx.x * 256 + threadIdx.x;
    if (g < N_PTS * BNUM) {
        const int n = g >> 6, b = g & 63;
        dataT[g] = data[b * N_PTS + n];
    }
    if (g < SNUM * WID) {
        const int s = g >> 7, j = g & 127;
        float acc = s_b1[j];
        #pragma unroll
        for (int d = 0; d < 8; d++) {
            const float val = v0[s*8 + d];
            #pragma unroll
            for (int k = 0; k < 5; k++) {
                const float f = (float)(1 << k);
                acc += __sinf(val*f) * s_w1[(d*10 + k)     * WID + j];
                acc += __cosf(val*f) * s_w1[(d*10 + 5 + k) * WID + j];
            }
        }
        h2g[g] = silu_f(acc);
    }
}

// ---------------------------------------------------------------------------
// K1: per s: filter-MLP over all n, fused with z[b,s,c] = silu((1/N) sum_n data[b,n]*filt1[s,n,c])
// grid 512 blocks (one per s), 256 threads.
// zout layout: [s][c][b]  (c*64+b contiguous per s)
// ---------------------------------------------------------------------------
__global__ __launch_bounds__(256) void k1_filt_z(
    const float* __restrict__ dataT, const float* __restrict__ v_last,
    const float* __restrict__ w1, const float* __restrict__ b1,
    const float* __restrict__ w2, const float* __restrict__ b2,
    const float* __restrict__ w3, const float* __restrict__ b3,
    float* __restrict__ zout)
{
    const int s = blockIdx.x;
    const int t = threadIdx.x;
    const int lane = t & 63;
    const int wave = t >> 6;

    __shared__ __align__(16) float lw1[20][20];
    __shared__ __align__(16) float lw2[20][20];
    __shared__ __align__(16) float lw3[20][20];
    __shared__ __align__(16) float lb1[20];
    __shared__ __align__(16) float lb2[20];
    __shared__ __align__(16) float lb3[20];
    __shared__ __align__(16) float filt[256][20];   // 20 KB
    __shared__ float red[4][64][20];                // 20 KB

    for (int v = t; v < 400; v += 256) {
        ((float*)lw1)[v] = w1[v];
        ((float*)lw2)[v] = w2[v];
        ((float*)lw3)[v] = w3[v];
    }
    if (t < 20) { lb1[t] = b1[t]; lb2[t] = b2[t]; lb3[t] = b3[t]; }

    // homography for this s: H = I + 0.1*[v_last, 0] reshaped 3x3
    float Hm[9];
    #pragma unroll
    for (int k = 0; k < 9; k++) Hm[k] = (k == 0 || k == 4 || k == 8) ? 1.f : 0.f;
    #pragma unroll
    for (int k = 0; k < 8; k++) Hm[k] += 0.1f * v_last[s*8 + k];

    float4 acc[5];
    #pragma unroll
    for (int q = 0; q < 5; q++) acc[q] = make_float4(0.f, 0.f, 0.f, 0.f);

    __syncthreads();

    for (int base = 0; base < N_PTS; base += 256) {
        const int tn = min(256, N_PTS - base);
        if (t < tn) {
            const int n = base + t;
            const int i = n / NSIDE;
            const int j = n - i * NSIDE;
            const float x = -1.f + (float)i * (2.f/39.f);
            const float y = -1.f + (float)j * (2.f/39.f);
            const float y0 = Hm[0]*x + Hm[1]*y + Hm[2];
            const float y1 = Hm[3]*x + Hm[4]*y + Hm[5];
            const float y2 = Hm[6]*x + Hm[7]*y + Hm[8];
            const float inv = 1.f / y2;
            const float tc0 = y0 * inv, tc1 = y1 * inv;

            float e[20];
            #pragma unroll
            for (int k = 0; k < 5; k++) {
                const float f = (float)(1 << k);
                e[k]      = __sinf(tc0*f); e[5+k]  = __cosf(tc0*f);
                e[10+k]   = __sinf(tc1*f); e[15+k] = __cosf(tc1*f);
            }
            // layer 1
            float4 h[5];
            #pragma unroll
            for (int q = 0; q < 5; q++) h[q] = ((const float4*)lb1)[q];
            #pragma unroll
            for (int ii = 0; ii < 20; ii++) {
                const float ei = e[ii];
                const float4* wr = (const float4*)&lw1[ii][0];
                #pragma unroll
                for (int q = 0; q < 5; q++) fma4(h[q], ei, wr[q]);
            }
            float hf[20];
            #pragma unroll
            for (int q = 0; q < 20; q++) hf[q] = silu_f(((float*)h)[q]);
            // layer 2
            float4 g2[5];
            #pragma unroll
            for (int q = 0; q < 5; q++) g2[q] = ((const float4*)lb2)[q];
            #pragma unroll
            for (int ii = 0; ii < 20; ii++) {
                const float ei = hf[ii];
                const float4* wr = (const float4*)&lw2[ii][0];
                #pragma unroll
                for (int q = 0; q < 5; q++) fma4(g2[q], ei, wr[q]);
            }
            float gf[20];
            #pragma unroll
            for (int q = 0; q < 20; q++) gf[q] = silu_f(((float*)g2)[q]);
            // layer 3 (no activation)
            float4 o[5];
            #pragma unroll
            for (int q = 0; q < 5; q++) o[q] = ((const float4*)lb3)[q];
            #pragma unroll
            for (int ii = 0; ii < 20; ii++) {
                const float ei = gf[ii];
                const float4* wr = (const float4*)&lw3[ii][0];
                #pragma unroll
                for (int q = 0; q < 5; q++) fma4(o[q], ei, wr[q]);
            }
            float4* frow = (float4*)&filt[t][0];
            #pragma unroll
            for (int q = 0; q < 5; q++) frow[q] = o[q];
        }
        __syncthreads();

        // accumulate: wave w handles its quarter of the tile's n range
        const int per = tn >> 2;
        const float* dp = dataT + (base + wave*per) * 64 + lane;
        const int fb = wave * per;
        #pragma unroll 4
        for (int k = 0; k < per; k++) {
            const float d = dp[k * 64];
            const float4* fr = (const float4*)&filt[fb + k][0];
            #pragma unroll
            for (int q = 0; q < 5; q++) fma4(acc[q], d, fr[q]);
        }
        __syncthreads();
    }

    // cross-wave reduction of acc over the 4 n-quarters
    float* af = (float*)acc;
    #pragma unroll
    for (int c = 0; c < 20; c++) red[wave][lane][c] = af[c];
    __syncthreads();
    for (int v = t; v < 1280; v += 256) {
        const int c = v >> 6, b = v & 63;
        const float sum = red[0][b][c] + red[1][b][c] + red[2][b][c] + red[3][b][c];
        zout[s * 1280 + v] = silu_f(sum * (1.f / (float)N_PTS));
    }
}

// ---------------------------------------------------------------------------
// KA: filt2[s][c*128+w] = h2[s] @ s_w2 + s_b2.  Tiled GEMM M=512,K=128,N=2560.
// grid (32 s-tiles of 16, 10 col-tiles of 256), 256 threads.
// ---------------------------------------------------------------------------
__global__ __launch_bounds__(256) void ka_filt2(
    const float* __restrict__ h2g, const float* __restrict__ s_w2,
    const float* __restrict__ s_b2, float* __restrict__ f2g)
{
    const int s0  = blockIdx.x * 16;
    const int col = blockIdx.y * 256 + threadIdx.x;
    const int t   = threadIdx.x;
    __shared__ __align__(16) float h2t[128][16];   // [i][ss]
    for (int v = t; v < 2048; v += 256) {
        const int i = v & 127, ss = v >> 7;
        h2t[i][ss] = h2g[(s0 + ss) * WID + i];
    }
    __syncthreads();
    float4 acc[4];
    #pragma unroll
    for (int q = 0; q < 4; q++) acc[q] = make_float4(0.f, 0.f, 0.f, 0.f);
    #pragma unroll 4
    for (int i = 0; i < 128; i++) {
        const float wv = s_w2[i * 2560 + col];
        const float4* hh = (const float4*)&h2t[i][0];
        #pragma unroll
        for (int q = 0; q < 4; q++) fma4(acc[q], wv, hh[q]);
    }
    const float bias = s_b2[col];
    const float* af = (const float*)acc;
    #pragma unroll
    for (int ss = 0; ss < 16; ss++)
        f2g[(s0 + ss) * 2560 + col] = af[ss] + bias;
}

// ---------------------------------------------------------------------------
// K2: split-K partials of out2[b][w] = sum_{s,c} z[s][c][b] * filt2[s][c][w]
// grid 256 blocks (2 s each), 256 threads. part layout [blk][b][w]
// ---------------------------------------------------------------------------
__global__ __launch_bounds__(256) void k2_contract(
    const float* __restrict__ zg, const float* __restrict__ f2g,
    float* __restrict__ part)
{
    const int blk = blockIdx.x;
    const int s0  = blk * 2;
    const int t   = threadIdx.x;
    __shared__ __align__(16) float zl[2560];   // [sp][c][b]
    __shared__ __align__(16) float fl[5120];   // [sp][c][w]
    for (int v = t; v < 2560; v += 256) zl[v] = zg[s0 * 1280 + v];
    for (int v = t; v < 5120; v += 256) fl[v] = f2g[s0 * 2560 + v];
    __syncthreads();
    const int w = t & 127, bh = t >> 7;
    float4 acc[8];
    #pragma unroll
    for (int q = 0; q < 8; q++) acc[q] = make_float4(0.f, 0.f, 0.f, 0.f);
    #pragma unroll 4
    for (int sc = 0; sc < 40; sc++) {
        const float f = fl[sc * 128 + w];
        const float4* zz = (const float4*)&zl[sc * 64 + bh * 32];
        #pragma unroll
        for (int q = 0; q < 8; q++) fma4(acc[q], f, zz[q]);
    }
    const float* af = (const float*)acc;
    #pragma unroll
    for (int idx = 0; idx < 32; idx++) {
        const int b = bh * 32 + idx;
        part[blk * 8192 + b * 128 + w] = af[idx];
    }
}

// ---------------------------------------------------------------------------
// K3: reduce partials, /S, then FC tail: 2x residual silu-FC + pool head.
// grid 64 blocks (one per b), 128 threads.
// ---------------------------------------------------------------------------
__global__ __launch_bounds__(128) void k3_tail(
    const float* __restrict__ part,
    const float* __restrict__ fc1w, const float* __restrict__ fc1b,
    const float* __restrict__ fc2w, const float* __restrict__ fc2b,
    const float* __restrict__ pw,   const float* __restrict__ pb,
    float* __restrict__ out)
{
    const int b = blockIdx.x, t = threadIdx.x;
    __shared__ float zb[128], r1[128], r2[128];
    float sum = 0.f;
    #pragma unroll 8
    for (int k = 0; k < 256; k++) sum += part[k * 8192 + b * 128 + t];
    zb[t] = sum * (1.f / (float)SNUM);
    __syncthreads();
    float a = fc1b[t];
    #pragma unroll 8
    for (int i = 0; i < 128; i++) a += zb[i] * fc1w[i * 128 + t];
    r1[t] = silu_f(a) + zb[t];
    __syncthreads();
    a = fc2b[t];
    #pragma unroll 8
    for (int i = 0; i < 128; i++) a += r1[i] * fc2w[i * 128 + t];
    r2[t] = silu_f(a) + r1[t];
    __syncthreads();
    if (t < 10) {
        float o = pb[t];
        #pragma unroll 8
        for (int i = 0; i < 128; i++) o += r2[i] * pw[i * 10 + t];
        out[b * 10 + t] = o;
    }
}

extern "C" void kernel_launch(void* const* d_in, const int* in_sizes, int n_in,
                              void* d_out, int out_size, void* d_ws, size_t ws_size,
                              hipStream_t stream) {
    const float* data   = (const float*)d_in[0];
    const float* v0     = (const float*)d_in[1];
    const float* v_last = (const float*)d_in[2];
    const float* fl_w1  = (const float*)d_in[3];
    const float* fl_b1  = (const float*)d_in[4];
    const float* fl_w2  = (const float*)d_in[5];
    const float* fl_b2  = (const float*)d_in[6];
    const float* fl_w3  = (const float*)d_in[7];
    const float* fl_b3  = (const float*)d_in[8];
    const float* s_w1   = (const float*)d_in[9];
    const float* s_b1   = (const float*)d_in[10];
    const float* s_w2   = (const float*)d_in[11];
    const float* s_b2   = (const float*)d_in[12];
    const float* fc1_w  = (const float*)d_in[13];
    const float* fc1_b  = (const float*)d_in[14];
    const float* fc2_w  = (const float*)d_in[15];
    const float* fc2_b  = (const float*)d_in[16];
    const float* pool_w = (const float*)d_in[17];
    const float* pool_b = (const float*)d_in[18];
    float* out = (float*)d_out;

    float* ws    = (float*)d_ws;
    float* dataT = ws;                      // 102400
    float* h2g   = dataT + 102400;          //  65536
    float* zg    = h2g   + 65536;           // 655360  [s][c][b]
    float* f2g   = zg    + 655360;          // 1310720 [s][c*128+w]
    float* part  = f2g   + 1310720;         // 2097152 [blk][b][w]
    // total ~16.9 MB of workspace

    k0_prep   <<<400, 256, 0, stream>>>(data, v0, s_w1, s_b1, dataT, h2g);
    k1_filt_z <<<512, 256, 0, stream>>>(dataT, v_last, fl_w1, fl_b1, fl_w2, fl_b2,
                                        fl_w3, fl_b3, zg);
    ka_filt2  <<<dim3(32, 10), 256, 0, stream>>>(h2g, s_w2, s_b2, f2g);
    k2_contract<<<256, 256, 0, stream>>>(zg, f2g, part);
    k3_tail   <<<64, 128, 0, stream>>>(part, fc1_w, fc1_b, fc2_w, fc2_b,
                                       pool_w, pool_b, out);
}